// Round 8
// baseline (211.163 us; speedup 1.0000x reference)
//
#include <hip/hip_runtime.h>

#define DF 128
#define SCAN_B 64
#define SCAN_T 256
#define GN 64           // nodes per gather_gemm block
#define MST 272         // LDS mean-row stride bytes (17*16; 68 dwords -> row shift 4 banks)

typedef __attribute__((ext_vector_type(8))) short short8;
typedef __attribute__((ext_vector_type(4))) float float4v;
typedef __attribute__((ext_vector_type(2))) float floatx2;

__device__ __forceinline__ unsigned int bf16rne(float f) {
    unsigned int u = __float_as_uint(f);
    return (u + 0x7fffu + ((u >> 16) & 1u)) >> 16;
}

// ---------------------------------------------------------------------------
// prep: fused (a) histogram of dst, (b) x fp32 -> bf16 xb AND fp8 xb8,
// (c) [Wl;Wr] swizzle into MFMA B-fragment order (bf16).
// ---------------------------------------------------------------------------
__global__ __launch_bounds__(256) void sage_prep(
    const float* __restrict__ x, const int* __restrict__ dst,
    const float* __restrict__ Wl, const float* __restrict__ Wr,
    int* __restrict__ cnt, char* __restrict__ xb, char* __restrict__ xb8,
    uint4* __restrict__ Bf, int N, int E)
{
    int tid = blockIdx.x * 256 + threadIdx.x;

    if (tid < N * 16) {                      // cast: 16 threads/row, 8 cols each
        int n = tid >> 4;
        int c = (tid & 15) * 8;
        const float4* xp = (const float4*)&x[(size_t)n * DF + c];
        float4 a = xp[0], b = xp[1];
        uint4 o;
        o.x = bf16rne(a.x) | (bf16rne(a.y) << 16);
        o.y = bf16rne(a.z) | (bf16rne(a.w) << 16);
        o.z = bf16rne(b.x) | (bf16rne(b.y) << 16);
        o.w = bf16rne(b.z) | (bf16rne(b.w) << 16);
        *(uint4*)(xb + (size_t)n * 256 + (size_t)(tid & 15) * 16) = o;

        int p0 = __builtin_amdgcn_cvt_pk_fp8_f32(a.x, a.y, 0, false);
        p0     = __builtin_amdgcn_cvt_pk_fp8_f32(a.z, a.w, p0, true);
        int p1 = __builtin_amdgcn_cvt_pk_fp8_f32(b.x, b.y, 0, false);
        p1     = __builtin_amdgcn_cvt_pk_fp8_f32(b.z, b.w, p1, true);
        uint2 o8; o8.x = (unsigned int)p0; o8.y = (unsigned int)p1;
        *(uint2*)(xb8 + (size_t)n * 128 + (size_t)(tid & 15) * 8) = o8;
    }

    if (tid < E) atomicAdd(&cnt[dst[tid]], 1);   // histogram

    if (tid < 4096) {                        // bprep
        int lane = tid & 63;
        int ctks = tid >> 6;
        int ks = ctks >> 3, ct = ctks & 7;
        int q = lane >> 4, m16 = lane & 15;
        int n = ct * 16 + m16;
        unsigned int w[4];
        #pragma unroll
        for (int p = 0; p < 4; ++p) {
            int k0 = ks * 32 + q * 8 + p * 2;
            float f0 = (k0 < DF) ? Wl[k0 * DF + n] : Wr[(k0 - DF) * DF + n];
            float f1 = (k0 + 1 < DF) ? Wl[(k0 + 1) * DF + n] : Wr[(k0 + 1 - DF) * DF + n];
            w[p] = bf16rne(f0) | (bf16rne(f1) << 16);
        }
        uint4 o = {w[0], w[1], w[2], w[3]};
        Bf[tid] = o;
    }
}

// ---------------------------------------------------------------------------
// scan pass 1: per-block reduce -> blktot
// ---------------------------------------------------------------------------
__global__ __launch_bounds__(SCAN_T) void scan_reduce(
    const int* __restrict__ cnt, int* __restrict__ blktot, int N)
{
    __shared__ int sdata[SCAN_T];
    const int t = threadIdx.x, b = blockIdx.x;
    const int chunk = (N + SCAN_B * SCAN_T - 1) / (SCAN_B * SCAN_T);
    const int lo = (b * SCAN_T + t) * chunk;
    const int hi = min(lo + chunk, N);
    int total = 0;
    for (int i = lo; i < hi; ++i) total += cnt[i];
    sdata[t] = total;
    __syncthreads();
    for (int s = SCAN_T / 2; s > 0; s >>= 1) {
        if (t < s) sdata[t] += sdata[t + s];
        __syncthreads();
    }
    if (t == 0) blktot[b] = sdata[0];
}

// ---------------------------------------------------------------------------
// scan pass 2: block-local base + LDS scan + write off/cur
// ---------------------------------------------------------------------------
__global__ __launch_bounds__(SCAN_T) void scan_write(
    int* __restrict__ off, int* __restrict__ cur,
    const int* __restrict__ blktot, int N, int E)
{
    __shared__ int sdata[SCAN_T];
    __shared__ int sbase;
    const int t = threadIdx.x, b = blockIdx.x;
    const int chunk = (N + SCAN_B * SCAN_T - 1) / (SCAN_B * SCAN_T);
    const int lo = (b * SCAN_T + t) * chunk;
    const int hi = min(lo + chunk, N);

    if (t == 0) {
        int s = 0;
        for (int i = 0; i < b; ++i) s += blktot[i];
        sbase = s;
    }
    int total = 0;
    for (int i = lo; i < hi; ++i) total += off[i];
    sdata[t] = total;
    __syncthreads();
    for (int s = 1; s < SCAN_T; s <<= 1) {
        int v = (t >= s) ? sdata[t - s] : 0;
        __syncthreads();
        sdata[t] += v;
        __syncthreads();
    }
    int running = sbase + ((t > 0) ? sdata[t - 1] : 0);
    for (int i = lo; i < hi; ++i) {
        int c = off[i];
        off[i] = running;
        cur[i] = running;
        running += c;
    }
    if (b == 0 && t == 0) off[N] = E;
}

// ---------------------------------------------------------------------------
// counting-sort of src by dst bucket
// ---------------------------------------------------------------------------
__global__ __launch_bounds__(256) void sage_sort(
    const int* __restrict__ src, const int* __restrict__ dst,
    int* __restrict__ cur, int* __restrict__ srt, int E)
{
    int e = blockIdx.x * 256 + threadIdx.x;
    if (e < E) {
        int p = atomicAdd(&cur[dst[e]], 1);
        srt[p] = src[e];
    }
}

// ---------------------------------------------------------------------------
// fused gather + gemm:
//   phase 1: fp8 gather — 8 lanes/node x 16B (=16 fp8 cols), 32 concurrent
//            node-groups per block, edge loop unrolled x8. Mean -> LDS bf16.
//   phase 2: MFMA 16x16x32 bf16 (GN=64 structure: 4 waves x 16 nodes x 8 ct)
//   epilogue: out = x + relu(C + bl)
// ---------------------------------------------------------------------------
__global__ __launch_bounds__(256) void sage_gg(
    const char* __restrict__ xb, const char* __restrict__ xb8,
    const int* __restrict__ off, const int* __restrict__ srt,
    const uint4* __restrict__ Bf, const float* __restrict__ bl,
    const float* __restrict__ x, float* __restrict__ out, int N)
{
    __shared__ char mlds[GN * MST];
    const int t = threadIdx.x;
    const int nb0 = blockIdx.x * GN;

    // ---- phase 1: 8 lanes/node, 32 nodes concurrent, 2 rounds ----
    {
        const int ln = t & 7;               // lane within node group
        const int g  = t >> 3;              // node group 0..31
        const size_t lnb = (size_t)ln * 16; // 16 fp8 bytes = cols ln*16..+15

        #pragma unroll
        for (int i = 0; i < GN / 32; ++i) {
            int nl = i * 32 + g;
            int n = nb0 + nl;
            float a[16];
            #pragma unroll
            for (int j = 0; j < 16; ++j) a[j] = 0.f;
            int deg = 1;
            if (n < N) {
                int start = off[n];
                int end   = off[n + 1];
                deg = max(end - start, 1);
                int e = start;
                for (; e + 8 <= end; e += 8) {
                    uint4 v[8];
                    #pragma unroll
                    for (int j = 0; j < 8; ++j) {
                        int s = srt[e + j];
                        v[j] = *(const uint4*)(xb8 + (size_t)s * 128 + lnb);
                    }
                    #pragma unroll
                    for (int j = 0; j < 8; ++j) {
                        floatx2 f;
                        f = __builtin_amdgcn_cvt_pk_f32_fp8(v[j].x, false); a[0] += f.x;  a[1] += f.y;
                        f = __builtin_amdgcn_cvt_pk_f32_fp8(v[j].x, true);  a[2] += f.x;  a[3] += f.y;
                        f = __builtin_amdgcn_cvt_pk_f32_fp8(v[j].y, false); a[4] += f.x;  a[5] += f.y;
                        f = __builtin_amdgcn_cvt_pk_f32_fp8(v[j].y, true);  a[6] += f.x;  a[7] += f.y;
                        f = __builtin_amdgcn_cvt_pk_f32_fp8(v[j].z, false); a[8] += f.x;  a[9] += f.y;
                        f = __builtin_amdgcn_cvt_pk_f32_fp8(v[j].z, true);  a[10] += f.x; a[11] += f.y;
                        f = __builtin_amdgcn_cvt_pk_f32_fp8(v[j].w, false); a[12] += f.x; a[13] += f.y;
                        f = __builtin_amdgcn_cvt_pk_f32_fp8(v[j].w, true);  a[14] += f.x; a[15] += f.y;
                    }
                }
                if (e + 4 <= end) {
                    uint4 v[4];
                    #pragma unroll
                    for (int j = 0; j < 4; ++j) {
                        int s = srt[e + j];
                        v[j] = *(const uint4*)(xb8 + (size_t)s * 128 + lnb);
                    }
                    #pragma unroll
                    for (int j = 0; j < 4; ++j) {
                        floatx2 f;
                        f = __builtin_amdgcn_cvt_pk_f32_fp8(v[j].x, false); a[0] += f.x;  a[1] += f.y;
                        f = __builtin_amdgcn_cvt_pk_f32_fp8(v[j].x, true);  a[2] += f.x;  a[3] += f.y;
                        f = __builtin_amdgcn_cvt_pk_f32_fp8(v[j].y, false); a[4] += f.x;  a[5] += f.y;
                        f = __builtin_amdgcn_cvt_pk_f32_fp8(v[j].y, true);  a[6] += f.x;  a[7] += f.y;
                        f = __builtin_amdgcn_cvt_pk_f32_fp8(v[j].z, false); a[8] += f.x;  a[9] += f.y;
                        f = __builtin_amdgcn_cvt_pk_f32_fp8(v[j].z, true);  a[10] += f.x; a[11] += f.y;
                        f = __builtin_amdgcn_cvt_pk_f32_fp8(v[j].w, false); a[12] += f.x; a[13] += f.y;
                        f = __builtin_amdgcn_cvt_pk_f32_fp8(v[j].w, true);  a[14] += f.x; a[15] += f.y;
                    }
                    e += 4;
                }
                for (; e < end; ++e) {
                    int s = srt[e];
                    uint4 v = *(const uint4*)(xb8 + (size_t)s * 128 + lnb);
                    floatx2 f;
                    f = __builtin_amdgcn_cvt_pk_f32_fp8(v.x, false); a[0] += f.x;  a[1] += f.y;
                    f = __builtin_amdgcn_cvt_pk_f32_fp8(v.x, true);  a[2] += f.x;  a[3] += f.y;
                    f = __builtin_amdgcn_cvt_pk_f32_fp8(v.y, false); a[4] += f.x;  a[5] += f.y;
                    f = __builtin_amdgcn_cvt_pk_f32_fp8(v.y, true);  a[6] += f.x;  a[7] += f.y;
                    f = __builtin_amdgcn_cvt_pk_f32_fp8(v.z, false); a[8] += f.x;  a[9] += f.y;
                    f = __builtin_amdgcn_cvt_pk_f32_fp8(v.z, true);  a[10] += f.x; a[11] += f.y;
                    f = __builtin_amdgcn_cvt_pk_f32_fp8(v.w, false); a[12] += f.x; a[13] += f.y;
                    f = __builtin_amdgcn_cvt_pk_f32_fp8(v.w, true);  a[14] += f.x; a[15] += f.y;
                }
            }
            float inv = 1.0f / (float)deg;
            uint4 o0, o1;
            o0.x = bf16rne(a[0] * inv)  | (bf16rne(a[1] * inv) << 16);
            o0.y = bf16rne(a[2] * inv)  | (bf16rne(a[3] * inv) << 16);
            o0.z = bf16rne(a[4] * inv)  | (bf16rne(a[5] * inv) << 16);
            o0.w = bf16rne(a[6] * inv)  | (bf16rne(a[7] * inv) << 16);
            o1.x = bf16rne(a[8] * inv)  | (bf16rne(a[9] * inv) << 16);
            o1.y = bf16rne(a[10] * inv) | (bf16rne(a[11] * inv) << 16);
            o1.z = bf16rne(a[12] * inv) | (bf16rne(a[13] * inv) << 16);
            o1.w = bf16rne(a[14] * inv) | (bf16rne(a[15] * inv) << 16);
            *(uint4*)(mlds + nl * MST + ln * 32) = o0;
            *(uint4*)(mlds + nl * MST + ln * 32 + 16) = o1;
        }
    }
    __syncthreads();

    // ---- phase 2: MFMA (4 waves x 16 nodes x 8 ct) ----
    const int wv = t >> 6;
    const int lane = t & 63;
    const int q = lane >> 4, m16 = lane & 15;
    const int nb = nb0 + wv * 16;
    const int am = min(nb + m16, N - 1);
    const short8* arow = (const short8*)(xb + (size_t)am * 256);
    const short8* mrow = (const short8*)(mlds + (wv * 16 + m16) * MST);
    const short8* bfp  = (const short8*)Bf;

    float4v acc[8];
    #pragma unroll
    for (int ct = 0; ct < 8; ++ct) acc[ct] = (float4v){0.f, 0.f, 0.f, 0.f};

    #pragma unroll
    for (int ks = 0; ks < 4; ++ks) {          // mean @ Wl
        short8 af = mrow[ks * 4 + q];
        #pragma unroll
        for (int ct = 0; ct < 8; ++ct) {
            short8 bfrag = bfp[(ks * 8 + ct) * 64 + lane];
            acc[ct] = __builtin_amdgcn_mfma_f32_16x16x32_bf16(af, bfrag, acc[ct], 0, 0, 0);
        }
    }
    #pragma unroll
    for (int ks = 0; ks < 4; ++ks) {          // x @ Wr
        short8 af = arow[ks * 4 + q];
        #pragma unroll
        for (int ct = 0; ct < 8; ++ct) {
            short8 bfrag = bfp[((ks + 4) * 8 + ct) * 64 + lane];
            acc[ct] = __builtin_amdgcn_mfma_f32_16x16x32_bf16(af, bfrag, acc[ct], 0, 0, 0);
        }
    }

    // ---- epilogue ----
    #pragma unroll
    for (int ct = 0; ct < 8; ++ct) {
        int col = ct * 16 + m16;
        float b = bl[col];
        #pragma unroll
        for (int r = 0; r < 4; ++r) {
            int n2 = nb + q * 4 + r;
            if (n2 < N) {
                size_t idx = (size_t)n2 * DF + col;
                out[idx] = x[idx] + fmaxf(acc[ct][r] + b, 0.f);
            }
        }
    }
}

extern "C" void kernel_launch(void* const* d_in, const int* in_sizes, int n_in,
                              void* d_out, int out_size, void* d_ws, size_t ws_size,
                              hipStream_t stream) {
    const float* x  = (const float*)d_in[0];
    const int*   ei = (const int*)d_in[1];
    const float* Wl = (const float*)d_in[2];
    const float* bl = (const float*)d_in[3];
    const float* Wr = (const float*)d_in[4];
    float* out = (float*)d_out;

    const int N = in_sizes[0] / DF;
    const int E = in_sizes[1] / 2;
    const int* src = ei;
    const int* dst = ei + E;

    // ws: off[N+1] | cur[N] | srt[E] | blktot[64] | pad16 | Bf[4096*16B]
    //     | xb[N*256B] | xb8[N*128B]
    int* off    = (int*)d_ws;
    int* cur    = off + (N + 1);
    int* srt    = cur + N;
    int* blktot = srt + E;
    size_t bfoff = ((size_t)(N + 1 + N + E + 64) * 4 + 15) & ~(size_t)15;
    uint4* Bf   = (uint4*)((char*)d_ws + bfoff);
    char* xb    = (char*)d_ws + bfoff + 4096 * 16;
    char* xb8   = xb + (size_t)N * 256;

    hipMemsetAsync(off, 0, (size_t)(N + 1) * sizeof(int), stream);

    int prepT = N * 16;
    sage_prep<<<(prepT + 255) / 256, 256, 0, stream>>>(
        x, dst, Wl, Wr, off, xb, xb8, Bf, N, E);
    scan_reduce<<<SCAN_B, SCAN_T, 0, stream>>>(off, blktot, N);
    scan_write<<<SCAN_B, SCAN_T, 0, stream>>>(off, cur, blktot, N, E);
    sage_sort<<<(E + 255) / 256, 256, 0, stream>>>(src, dst, cur, srt, E);
    sage_gg<<<(N + GN - 1) / GN, 256, 0, stream>>>(
        xb, xb8, off, srt, Bf, bl, x, out, N);
}

// Round 9
// 202.853 us; speedup vs baseline: 1.0410x; 1.0410x over previous
//
#include <hip/hip_runtime.h>

#define DF 128
#define SCAN_B 64
#define SCAN_T 256
#define GN 64           // nodes per gather_gemm block
#define MST 272         // LDS mean-row stride bytes (17*16)

typedef __attribute__((ext_vector_type(8))) short short8;
typedef __attribute__((ext_vector_type(4))) float float4v;
typedef __attribute__((ext_vector_type(2))) float floatx2;

__device__ __forceinline__ unsigned int bf16rne(float f) {
    unsigned int u = __float_as_uint(f);
    return (u + 0x7fffu + ((u >> 16) & 1u)) >> 16;
}

// ---------------------------------------------------------------------------
// prep: fused (a) histogram of dst, (b) x fp32 -> bf16 xb AND fp8 xb8,
// (c) [Wl;Wr] swizzle into MFMA B-fragment order (bf16).
// ---------------------------------------------------------------------------
__global__ __launch_bounds__(256) void sage_prep(
    const float* __restrict__ x, const int* __restrict__ dst,
    const float* __restrict__ Wl, const float* __restrict__ Wr,
    int* __restrict__ cnt, char* __restrict__ xb, char* __restrict__ xb8,
    uint4* __restrict__ Bf, int N, int E)
{
    int tid = blockIdx.x * 256 + threadIdx.x;

    if (tid < N * 16) {                      // cast: 16 threads/row, 8 cols each
        int n = tid >> 4;
        int c = (tid & 15) * 8;
        const float4* xp = (const float4*)&x[(size_t)n * DF + c];
        float4 a = xp[0], b = xp[1];
        uint4 o;
        o.x = bf16rne(a.x) | (bf16rne(a.y) << 16);
        o.y = bf16rne(a.z) | (bf16rne(a.w) << 16);
        o.z = bf16rne(b.x) | (bf16rne(b.y) << 16);
        o.w = bf16rne(b.z) | (bf16rne(b.w) << 16);
        *(uint4*)(xb + (size_t)n * 256 + (size_t)(tid & 15) * 16) = o;

        int p0 = __builtin_amdgcn_cvt_pk_fp8_f32(a.x, a.y, 0, false);
        p0     = __builtin_amdgcn_cvt_pk_fp8_f32(a.z, a.w, p0, true);
        int p1 = __builtin_amdgcn_cvt_pk_fp8_f32(b.x, b.y, 0, false);
        p1     = __builtin_amdgcn_cvt_pk_fp8_f32(b.z, b.w, p1, true);
        uint2 o8; o8.x = (unsigned int)p0; o8.y = (unsigned int)p1;
        *(uint2*)(xb8 + (size_t)n * 128 + (size_t)(tid & 15) * 8) = o8;
    }

    if (tid < E) atomicAdd(&cnt[dst[tid]], 1);   // histogram

    if (tid < 4096) {                        // bprep
        int lane = tid & 63;
        int ctks = tid >> 6;
        int ks = ctks >> 3, ct = ctks & 7;
        int q = lane >> 4, m16 = lane & 15;
        int n = ct * 16 + m16;
        unsigned int w[4];
        #pragma unroll
        for (int p = 0; p < 4; ++p) {
            int k0 = ks * 32 + q * 8 + p * 2;
            float f0 = (k0 < DF) ? Wl[k0 * DF + n] : Wr[(k0 - DF) * DF + n];
            float f1 = (k0 + 1 < DF) ? Wl[(k0 + 1) * DF + n] : Wr[(k0 + 1 - DF) * DF + n];
            w[p] = bf16rne(f0) | (bf16rne(f1) << 16);
        }
        uint4 o = {w[0], w[1], w[2], w[3]};
        Bf[tid] = o;
    }
}

// ---------------------------------------------------------------------------
// scan pass 1: per-block reduce -> blktot
// ---------------------------------------------------------------------------
__global__ __launch_bounds__(SCAN_T) void scan_reduce(
    const int* __restrict__ cnt, int* __restrict__ blktot, int N)
{
    __shared__ int sdata[SCAN_T];
    const int t = threadIdx.x, b = blockIdx.x;
    const int chunk = (N + SCAN_B * SCAN_T - 1) / (SCAN_B * SCAN_T);
    const int lo = (b * SCAN_T + t) * chunk;
    const int hi = min(lo + chunk, N);
    int total = 0;
    for (int i = lo; i < hi; ++i) total += cnt[i];
    sdata[t] = total;
    __syncthreads();
    for (int s = SCAN_T / 2; s > 0; s >>= 1) {
        if (t < s) sdata[t] += sdata[t + s];
        __syncthreads();
    }
    if (t == 0) blktot[b] = sdata[0];
}

// ---------------------------------------------------------------------------
// scan pass 2: block-local base + LDS scan + write off/cur
// ---------------------------------------------------------------------------
__global__ __launch_bounds__(SCAN_T) void scan_write(
    int* __restrict__ off, int* __restrict__ cur,
    const int* __restrict__ blktot, int N, int E)
{
    __shared__ int sdata[SCAN_T];
    __shared__ int sbase;
    const int t = threadIdx.x, b = blockIdx.x;
    const int chunk = (N + SCAN_B * SCAN_T - 1) / (SCAN_B * SCAN_T);
    const int lo = (b * SCAN_T + t) * chunk;
    const int hi = min(lo + chunk, N);

    if (t == 0) {
        int s = 0;
        for (int i = 0; i < b; ++i) s += blktot[i];
        sbase = s;
    }
    int total = 0;
    for (int i = lo; i < hi; ++i) total += off[i];
    sdata[t] = total;
    __syncthreads();
    for (int s = 1; s < SCAN_T; s <<= 1) {
        int v = (t >= s) ? sdata[t - s] : 0;
        __syncthreads();
        sdata[t] += v;
        __syncthreads();
    }
    int running = sbase + ((t > 0) ? sdata[t - 1] : 0);
    for (int i = lo; i < hi; ++i) {
        int c = off[i];
        off[i] = running;
        cur[i] = running;
        running += c;
    }
    if (b == 0 && t == 0) off[N] = E;
}

// ---------------------------------------------------------------------------
// counting-sort of src by dst bucket
// ---------------------------------------------------------------------------
__global__ __launch_bounds__(256) void sage_sort(
    const int* __restrict__ src, const int* __restrict__ dst,
    int* __restrict__ cur, int* __restrict__ srt, int E)
{
    int e = blockIdx.x * 256 + threadIdx.x;
    if (e < E) {
        int p = atomicAdd(&cur[dst[e]], 1);
        srt[p] = src[e];
    }
}

// ---------------------------------------------------------------------------
// fused gather + gemm:
//   phase 1: fp8 gather — 32 lanes/node x 4B dword (=4 fp8 cols/lane);
//            2 nodes/wave (minimal degree divergence), 8 rounds for GN=64;
//            edge loop unrolled x8 (8 dword loads in flight); only 4 fp32
//            accumulators/lane -> lean VGPR. Mean -> LDS bf16.
//   phase 2: MFMA 16x16x32 bf16 (4 waves x 16 nodes x 8 ct)
//   epilogue: out = x + relu(C + bl)
// ---------------------------------------------------------------------------
__global__ __launch_bounds__(256) void sage_gg(
    const char* __restrict__ xb, const char* __restrict__ xb8,
    const int* __restrict__ off, const int* __restrict__ srt,
    const uint4* __restrict__ Bf, const float* __restrict__ bl,
    const float* __restrict__ x, float* __restrict__ out, int N)
{
    __shared__ char mlds[GN * MST];
    const int t = threadIdx.x;
    const int nb0 = blockIdx.x * GN;
    const int wv = t >> 6;
    const int lane = t & 63;

    // ---- phase 1: 32 lanes/node, 2 nodes per wave, 8 rounds ----
    {
        const int half = lane >> 5;          // node slot within wave
        const int ln = lane & 31;            // lane within 32-group
        const size_t lnb = (size_t)ln * 4;   // dword offset in 128B fp8 row

        #pragma unroll
        for (int i = 0; i < GN / 8; ++i) {
            int nl = i * 8 + wv * 2 + half;
            int n = nb0 + nl;
            float a0 = 0.f, a1 = 0.f, a2 = 0.f, a3 = 0.f;
            int deg = 1;
            if (n < N) {
                int start = off[n];
                int end   = off[n + 1];
                deg = max(end - start, 1);
                int e = start;
                for (; e + 8 <= end; e += 8) {
                    int s[8];
                    unsigned int v[8];
                    #pragma unroll
                    for (int j = 0; j < 8; ++j) s[j] = srt[e + j];
                    #pragma unroll
                    for (int j = 0; j < 8; ++j)
                        v[j] = *(const unsigned int*)(xb8 + (size_t)s[j] * 128 + lnb);
                    #pragma unroll
                    for (int j = 0; j < 8; ++j) {
                        floatx2 f0 = __builtin_amdgcn_cvt_pk_f32_fp8(v[j], false);
                        floatx2 f1 = __builtin_amdgcn_cvt_pk_f32_fp8(v[j], true);
                        a0 += f0.x; a1 += f0.y; a2 += f1.x; a3 += f1.y;
                    }
                }
                if (e + 4 <= end) {
                    int s[4];
                    unsigned int v[4];
                    #pragma unroll
                    for (int j = 0; j < 4; ++j) s[j] = srt[e + j];
                    #pragma unroll
                    for (int j = 0; j < 4; ++j)
                        v[j] = *(const unsigned int*)(xb8 + (size_t)s[j] * 128 + lnb);
                    #pragma unroll
                    for (int j = 0; j < 4; ++j) {
                        floatx2 f0 = __builtin_amdgcn_cvt_pk_f32_fp8(v[j], false);
                        floatx2 f1 = __builtin_amdgcn_cvt_pk_f32_fp8(v[j], true);
                        a0 += f0.x; a1 += f0.y; a2 += f1.x; a3 += f1.y;
                    }
                    e += 4;
                }
                for (; e < end; ++e) {
                    unsigned int v = *(const unsigned int*)(xb8 + (size_t)srt[e] * 128 + lnb);
                    floatx2 f0 = __builtin_amdgcn_cvt_pk_f32_fp8(v, false);
                    floatx2 f1 = __builtin_amdgcn_cvt_pk_f32_fp8(v, true);
                    a0 += f0.x; a1 += f0.y; a2 += f1.x; a3 += f1.y;
                }
            }
            float inv = 1.0f / (float)deg;
            uint2 o;
            o.x = bf16rne(a0 * inv) | (bf16rne(a1 * inv) << 16);
            o.y = bf16rne(a2 * inv) | (bf16rne(a3 * inv) << 16);
            *(uint2*)(mlds + nl * MST + ln * 8) = o;   // cols ln*4..+3 @ byte ln*8
        }
    }
    __syncthreads();

    // ---- phase 2: MFMA (4 waves x 16 nodes x 8 ct) ----
    const int q = lane >> 4, m16 = lane & 15;
    const int nb = nb0 + wv * 16;
    const int am = min(nb + m16, N - 1);
    const short8* arow = (const short8*)(xb + (size_t)am * 256);
    const short8* mrow = (const short8*)(mlds + (wv * 16 + m16) * MST);
    const short8* bfp  = (const short8*)Bf;

    float4v acc[8];
    #pragma unroll
    for (int ct = 0; ct < 8; ++ct) acc[ct] = (float4v){0.f, 0.f, 0.f, 0.f};

    #pragma unroll
    for (int ks = 0; ks < 4; ++ks) {          // mean @ Wl
        short8 af = mrow[ks * 4 + q];
        #pragma unroll
        for (int ct = 0; ct < 8; ++ct) {
            short8 bfrag = bfp[(ks * 8 + ct) * 64 + lane];
            acc[ct] = __builtin_amdgcn_mfma_f32_16x16x32_bf16(af, bfrag, acc[ct], 0, 0, 0);
        }
    }
    #pragma unroll
    for (int ks = 0; ks < 4; ++ks) {          // x @ Wr
        short8 af = arow[ks * 4 + q];
        #pragma unroll
        for (int ct = 0; ct < 8; ++ct) {
            short8 bfrag = bfp[((ks + 4) * 8 + ct) * 64 + lane];
            acc[ct] = __builtin_amdgcn_mfma_f32_16x16x32_bf16(af, bfrag, acc[ct], 0, 0, 0);
        }
    }

    // ---- epilogue ----
    #pragma unroll
    for (int ct = 0; ct < 8; ++ct) {
        int col = ct * 16 + m16;
        float b = bl[col];
        #pragma unroll
        for (int r = 0; r < 4; ++r) {
            int n2 = nb + q * 4 + r;
            if (n2 < N) {
                size_t idx = (size_t)n2 * DF + col;
                out[idx] = x[idx] + fmaxf(acc[ct][r] + b, 0.f);
            }
        }
    }
}

extern "C" void kernel_launch(void* const* d_in, const int* in_sizes, int n_in,
                              void* d_out, int out_size, void* d_ws, size_t ws_size,
                              hipStream_t stream) {
    const float* x  = (const float*)d_in[0];
    const int*   ei = (const int*)d_in[1];
    const float* Wl = (const float*)d_in[2];
    const float* bl = (const float*)d_in[3];
    const float* Wr = (const float*)d_in[4];
    float* out = (float*)d_out;

    const int N = in_sizes[0] / DF;
    const int E = in_sizes[1] / 2;
    const int* src = ei;
    const int* dst = ei + E;

    // ws: off[N+1] | cur[N] | srt[E] | blktot[64] | pad16 | Bf[4096*16B]
    //     | xb[N*256B] | xb8[N*128B]
    int* off    = (int*)d_ws;
    int* cur    = off + (N + 1);
    int* srt    = cur + N;
    int* blktot = srt + E;
    size_t bfoff = ((size_t)(N + 1 + N + E + 64) * 4 + 15) & ~(size_t)15;
    uint4* Bf   = (uint4*)((char*)d_ws + bfoff);
    char* xb    = (char*)d_ws + bfoff + 4096 * 16;
    char* xb8   = xb + (size_t)N * 256;

    hipMemsetAsync(off, 0, (size_t)(N + 1) * sizeof(int), stream);

    int prepT = N * 16;
    sage_prep<<<(prepT + 255) / 256, 256, 0, stream>>>(
        x, dst, Wl, Wr, off, xb, xb8, Bf, N, E);
    scan_reduce<<<SCAN_B, SCAN_T, 0, stream>>>(off, blktot, N);
    scan_write<<<SCAN_B, SCAN_T, 0, stream>>>(off, cur, blktot, N, E);
    sage_sort<<<(E + 255) / 256, 256, 0, stream>>>(src, dst, cur, srt, E);
    sage_gg<<<(N + GN - 1) / GN, 256, 0, stream>>>(
        xb, xb8, off, srt, Bf, bl, x, out, N);
}

// Round 10
// 200.416 us; speedup vs baseline: 1.0536x; 1.0122x over previous
//
#include <hip/hip_runtime.h>

#define DF 128
#define SCAN_B 64
#define SCAN_T 256
#define GN 64           // nodes per gather_gemm block
#define MST 272         // LDS mean-row stride bytes (17*16)
#define ECAP 2048       // staged edges per block (Poisson(12.5)*64 ~ 800; overflow -> global)

typedef __attribute__((ext_vector_type(8))) short short8;
typedef __attribute__((ext_vector_type(4))) float float4v;
typedef __attribute__((ext_vector_type(2))) float floatx2;

__device__ __forceinline__ unsigned int bf16rne(float f) {
    unsigned int u = __float_as_uint(f);
    return (u + 0x7fffu + ((u >> 16) & 1u)) >> 16;
}

// ---------------------------------------------------------------------------
// prep: fused (a) histogram of dst, (b) x fp32 -> bf16 xb AND fp8 xb8,
// (c) [Wl;Wr] swizzle into MFMA B-fragment order (bf16).
// ---------------------------------------------------------------------------
__global__ __launch_bounds__(256) void sage_prep(
    const float* __restrict__ x, const int* __restrict__ dst,
    const float* __restrict__ Wl, const float* __restrict__ Wr,
    int* __restrict__ cnt, char* __restrict__ xb, char* __restrict__ xb8,
    uint4* __restrict__ Bf, int N, int E)
{
    int tid = blockIdx.x * 256 + threadIdx.x;

    if (tid < N * 16) {                      // cast: 16 threads/row, 8 cols each
        int n = tid >> 4;
        int c = (tid & 15) * 8;
        const float4* xp = (const float4*)&x[(size_t)n * DF + c];
        float4 a = xp[0], b = xp[1];
        uint4 o;
        o.x = bf16rne(a.x) | (bf16rne(a.y) << 16);
        o.y = bf16rne(a.z) | (bf16rne(a.w) << 16);
        o.z = bf16rne(b.x) | (bf16rne(b.y) << 16);
        o.w = bf16rne(b.z) | (bf16rne(b.w) << 16);
        *(uint4*)(xb + (size_t)n * 256 + (size_t)(tid & 15) * 16) = o;

        int p0 = __builtin_amdgcn_cvt_pk_fp8_f32(a.x, a.y, 0, false);
        p0     = __builtin_amdgcn_cvt_pk_fp8_f32(a.z, a.w, p0, true);
        int p1 = __builtin_amdgcn_cvt_pk_fp8_f32(b.x, b.y, 0, false);
        p1     = __builtin_amdgcn_cvt_pk_fp8_f32(b.z, b.w, p1, true);
        uint2 o8; o8.x = (unsigned int)p0; o8.y = (unsigned int)p1;
        *(uint2*)(xb8 + (size_t)n * 128 + (size_t)(tid & 15) * 8) = o8;
    }

    if (tid < E) atomicAdd(&cnt[dst[tid]], 1);   // histogram

    if (tid < 4096) {                        // bprep
        int lane = tid & 63;
        int ctks = tid >> 6;
        int ks = ctks >> 3, ct = ctks & 7;
        int q = lane >> 4, m16 = lane & 15;
        int n = ct * 16 + m16;
        unsigned int w[4];
        #pragma unroll
        for (int p = 0; p < 4; ++p) {
            int k0 = ks * 32 + q * 8 + p * 2;
            float f0 = (k0 < DF) ? Wl[k0 * DF + n] : Wr[(k0 - DF) * DF + n];
            float f1 = (k0 + 1 < DF) ? Wl[(k0 + 1) * DF + n] : Wr[(k0 + 1 - DF) * DF + n];
            w[p] = bf16rne(f0) | (bf16rne(f1) << 16);
        }
        uint4 o = {w[0], w[1], w[2], w[3]};
        Bf[tid] = o;
    }
}

// ---------------------------------------------------------------------------
// scan pass 1: per-block reduce -> blktot
// ---------------------------------------------------------------------------
__global__ __launch_bounds__(SCAN_T) void scan_reduce(
    const int* __restrict__ cnt, int* __restrict__ blktot, int N)
{
    __shared__ int sdata[SCAN_T];
    const int t = threadIdx.x, b = blockIdx.x;
    const int chunk = (N + SCAN_B * SCAN_T - 1) / (SCAN_B * SCAN_T);
    const int lo = (b * SCAN_T + t) * chunk;
    const int hi = min(lo + chunk, N);
    int total = 0;
    for (int i = lo; i < hi; ++i) total += cnt[i];
    sdata[t] = total;
    __syncthreads();
    for (int s = SCAN_T / 2; s > 0; s >>= 1) {
        if (t < s) sdata[t] += sdata[t + s];
        __syncthreads();
    }
    if (t == 0) blktot[b] = sdata[0];
}

// ---------------------------------------------------------------------------
// scan pass 2: block-local base + LDS scan + write off/cur
// ---------------------------------------------------------------------------
__global__ __launch_bounds__(SCAN_T) void scan_write(
    int* __restrict__ off, int* __restrict__ cur,
    const int* __restrict__ blktot, int N, int E)
{
    __shared__ int sdata[SCAN_T];
    __shared__ int sbase;
    const int t = threadIdx.x, b = blockIdx.x;
    const int chunk = (N + SCAN_B * SCAN_T - 1) / (SCAN_B * SCAN_T);
    const int lo = (b * SCAN_T + t) * chunk;
    const int hi = min(lo + chunk, N);

    if (t == 0) {
        int s = 0;
        for (int i = 0; i < b; ++i) s += blktot[i];
        sbase = s;
    }
    int total = 0;
    for (int i = lo; i < hi; ++i) total += off[i];
    sdata[t] = total;
    __syncthreads();
    for (int s = 1; s < SCAN_T; s <<= 1) {
        int v = (t >= s) ? sdata[t - s] : 0;
        __syncthreads();
        sdata[t] += v;
        __syncthreads();
    }
    int running = sbase + ((t > 0) ? sdata[t - 1] : 0);
    for (int i = lo; i < hi; ++i) {
        int c = off[i];
        off[i] = running;
        cur[i] = running;
        running += c;
    }
    if (b == 0 && t == 0) off[N] = E;
}

// ---------------------------------------------------------------------------
// counting-sort of src by dst bucket
// ---------------------------------------------------------------------------
__global__ __launch_bounds__(256) void sage_sort(
    const int* __restrict__ src, const int* __restrict__ dst,
    int* __restrict__ cur, int* __restrict__ srt, int E)
{
    int e = blockIdx.x * 256 + threadIdx.x;
    if (e < E) {
        int p = atomicAdd(&cur[dst[e]], 1);
        srt[p] = src[e];
    }
}

// ---------------------------------------------------------------------------
// fused gather + gemm:
//   phase 0: stage this block's contiguous srt segment (and off[] slice)
//            into LDS — removes the dependent index round-trip from the
//            gather's critical path (ds_read ~30cyc vs global ~400cyc).
//   phase 1: fp8 gather — 32 lanes/node x 4B dword; 2 nodes/wave; edge loop
//            unrolled x8 (8 independent row loads per round trip).
//   phase 2: MFMA 16x16x32 bf16 (4 waves x 16 nodes x 8 ct)
//   epilogue: out = x + relu(C + bl)
// ---------------------------------------------------------------------------
__global__ __launch_bounds__(256) void sage_gg(
    const char* __restrict__ xb, const char* __restrict__ xb8,
    const int* __restrict__ off, const int* __restrict__ srt,
    const uint4* __restrict__ Bf, const float* __restrict__ bl,
    const float* __restrict__ x, float* __restrict__ out, int N)
{
    __shared__ char mlds[GN * MST];
    __shared__ int selds[ECAP];
    __shared__ int solds[GN + 1];
    const int t = threadIdx.x;
    const int nb0 = blockIdx.x * GN;
    const int wv = t >> 6;
    const int lane = t & 63;

    // ---- phase 0: stage off-slice and srt segment ----
    const int nend = min(nb0 + GN, N);
    const int nloc = nend - nb0;
    if (t <= nloc) solds[t] = off[nb0 + t];
    const int ebase = off[nb0];
    const int ecnt  = min(off[nend] - ebase, ECAP);
    for (int i = t; i < ecnt; i += 256) selds[i] = srt[ebase + i];
    __syncthreads();

    // ---- phase 1: 32 lanes/node, 2 nodes per wave, 8 rounds ----
    {
        const int half = lane >> 5;          // node slot within wave
        const int ln = lane & 31;            // lane within 32-group
        const size_t lnb = (size_t)ln * 4;   // dword offset in 128B fp8 row

        #pragma unroll
        for (int i = 0; i < GN / 8; ++i) {
            int nl = i * 8 + wv * 2 + half;
            int n = nb0 + nl;
            float a0 = 0.f, a1 = 0.f, a2 = 0.f, a3 = 0.f;
            int deg = 1;
            if (n < N) {
                int start = solds[nl];
                int end   = solds[nl + 1];
                deg = max(end - start, 1);
                int e = start;
                for (; e + 8 <= end; e += 8) {
                    int s[8];
                    unsigned int v[8];
                    #pragma unroll
                    for (int j = 0; j < 8; ++j) {
                        int er = e + j - ebase;
                        s[j] = (er < ECAP) ? selds[er] : srt[e + j];
                    }
                    #pragma unroll
                    for (int j = 0; j < 8; ++j)
                        v[j] = *(const unsigned int*)(xb8 + (size_t)s[j] * 128 + lnb);
                    #pragma unroll
                    for (int j = 0; j < 8; ++j) {
                        floatx2 f0 = __builtin_amdgcn_cvt_pk_f32_fp8(v[j], false);
                        floatx2 f1 = __builtin_amdgcn_cvt_pk_f32_fp8(v[j], true);
                        a0 += f0.x; a1 += f0.y; a2 += f1.x; a3 += f1.y;
                    }
                }
                if (e + 4 <= end) {
                    int s[4];
                    unsigned int v[4];
                    #pragma unroll
                    for (int j = 0; j < 4; ++j) {
                        int er = e + j - ebase;
                        s[j] = (er < ECAP) ? selds[er] : srt[e + j];
                    }
                    #pragma unroll
                    for (int j = 0; j < 4; ++j)
                        v[j] = *(const unsigned int*)(xb8 + (size_t)s[j] * 128 + lnb);
                    #pragma unroll
                    for (int j = 0; j < 4; ++j) {
                        floatx2 f0 = __builtin_amdgcn_cvt_pk_f32_fp8(v[j], false);
                        floatx2 f1 = __builtin_amdgcn_cvt_pk_f32_fp8(v[j], true);
                        a0 += f0.x; a1 += f0.y; a2 += f1.x; a3 += f1.y;
                    }
                    e += 4;
                }
                for (; e < end; ++e) {
                    int er = e - ebase;
                    int s = (er < ECAP) ? selds[er] : srt[e];
                    unsigned int v = *(const unsigned int*)(xb8 + (size_t)s * 128 + lnb);
                    floatx2 f0 = __builtin_amdgcn_cvt_pk_f32_fp8(v, false);
                    floatx2 f1 = __builtin_amdgcn_cvt_pk_f32_fp8(v, true);
                    a0 += f0.x; a1 += f0.y; a2 += f1.x; a3 += f1.y;
                }
            }
            float inv = 1.0f / (float)deg;
            uint2 o;
            o.x = bf16rne(a0 * inv) | (bf16rne(a1 * inv) << 16);
            o.y = bf16rne(a2 * inv) | (bf16rne(a3 * inv) << 16);
            *(uint2*)(mlds + nl * MST + ln * 8) = o;
        }
    }
    __syncthreads();

    // ---- phase 2: MFMA (4 waves x 16 nodes x 8 ct) ----
    const int q = lane >> 4, m16 = lane & 15;
    const int nb = nb0 + wv * 16;
    const int am = min(nb + m16, N - 1);
    const short8* arow = (const short8*)(xb + (size_t)am * 256);
    const short8* mrow = (const short8*)(mlds + (wv * 16 + m16) * MST);
    const short8* bfp  = (const short8*)Bf;

    float4v acc[8];
    #pragma unroll
    for (int ct = 0; ct < 8; ++ct) acc[ct] = (float4v){0.f, 0.f, 0.f, 0.f};

    #pragma unroll
    for (int ks = 0; ks < 4; ++ks) {          // mean @ Wl
        short8 af = mrow[ks * 4 + q];
        #pragma unroll
        for (int ct = 0; ct < 8; ++ct) {
            short8 bfrag = bfp[(ks * 8 + ct) * 64 + lane];
            acc[ct] = __builtin_amdgcn_mfma_f32_16x16x32_bf16(af, bfrag, acc[ct], 0, 0, 0);
        }
    }
    #pragma unroll
    for (int ks = 0; ks < 4; ++ks) {          // x @ Wr
        short8 af = arow[ks * 4 + q];
        #pragma unroll
        for (int ct = 0; ct < 8; ++ct) {
            short8 bfrag = bfp[((ks + 4) * 8 + ct) * 64 + lane];
            acc[ct] = __builtin_amdgcn_mfma_f32_16x16x32_bf16(af, bfrag, acc[ct], 0, 0, 0);
        }
    }

    // ---- epilogue ----
    #pragma unroll
    for (int ct = 0; ct < 8; ++ct) {
        int col = ct * 16 + m16;
        float b = bl[col];
        #pragma unroll
        for (int r = 0; r < 4; ++r) {
            int n2 = nb + q * 4 + r;
            if (n2 < N) {
                size_t idx = (size_t)n2 * DF + col;
                out[idx] = x[idx] + fmaxf(acc[ct][r] + b, 0.f);
            }
        }
    }
}

extern "C" void kernel_launch(void* const* d_in, const int* in_sizes, int n_in,
                              void* d_out, int out_size, void* d_ws, size_t ws_size,
                              hipStream_t stream) {
    const float* x  = (const float*)d_in[0];
    const int*   ei = (const int*)d_in[1];
    const float* Wl = (const float*)d_in[2];
    const float* bl = (const float*)d_in[3];
    const float* Wr = (const float*)d_in[4];
    float* out = (float*)d_out;

    const int N = in_sizes[0] / DF;
    const int E = in_sizes[1] / 2;
    const int* src = ei;
    const int* dst = ei + E;

    // ws: off[N+1] | cur[N] | srt[E] | blktot[64] | pad16 | Bf[4096*16B]
    //     | xb[N*256B] | xb8[N*128B]
    int* off    = (int*)d_ws;
    int* cur    = off + (N + 1);
    int* srt    = cur + N;
    int* blktot = srt + E;
    size_t bfoff = ((size_t)(N + 1 + N + E + 64) * 4 + 15) & ~(size_t)15;
    uint4* Bf   = (uint4*)((char*)d_ws + bfoff);
    char* xb    = (char*)d_ws + bfoff + 4096 * 16;
    char* xb8   = xb + (size_t)N * 256;

    hipMemsetAsync(off, 0, (size_t)(N + 1) * sizeof(int), stream);

    int prepT = N * 16;
    sage_prep<<<(prepT + 255) / 256, 256, 0, stream>>>(
        x, dst, Wl, Wr, off, xb, xb8, Bf, N, E);
    scan_reduce<<<SCAN_B, SCAN_T, 0, stream>>>(off, blktot, N);
    scan_write<<<SCAN_B, SCAN_T, 0, stream>>>(off, cur, blktot, N, E);
    sage_sort<<<(E + 255) / 256, 256, 0, stream>>>(src, dst, cur, srt, E);
    sage_gg<<<(N + GN - 1) / GN, 256, 0, stream>>>(
        xb, xb8, off, srt, Bf, bl, x, out, N);
}